// Round 2
// baseline (4581.825 us; speedup 1.0000x reference)
//
#include <hip/hip_runtime.h>

// GraphSAGE 2-layer, fp32. N=50000 nodes, E=800000 edges, 128 -> 256 -> 256.
// Phases: degree -> deg_inv -> scatter0(128ch, atomics) -> gemm0(+relu, h1 in d_out)
//         -> scatter1(256ch, atomics) -> gemm1 (in-place on d_out).
// gemm1 uses a full-width 64x256 tile per block so in-place read/write rows are
// block-local (fixes the round-1 cross-block race between column tiles).

#define NN 50000
#define NE 800000
#define C0 128
#define C1 256

__global__ __launch_bounds__(256) void k_degree(const int* __restrict__ dst,
                                                float* __restrict__ deg) {
    int e = blockIdx.x * 256 + threadIdx.x;
    if (e < NE) atomicAdd(&deg[dst[e]], 1.0f);
}

__global__ __launch_bounds__(256) void k_deginv(float* __restrict__ deg) {
    int i = blockIdx.x * 256 + threadIdx.x;
    if (i < NN) deg[i] = 1.0f / fmaxf(deg[i], 1.0f);
}

// One float4 (4 channels) per thread; C/4 threads per edge.
template <int C, int SHIFT>
__global__ __launch_bounds__(256) void k_scatter(const float* __restrict__ feat,
                                                 const int* __restrict__ src,
                                                 const int* __restrict__ dst,
                                                 const float* __restrict__ ew,
                                                 float* __restrict__ agg) {
    long long gid = (long long)blockIdx.x * 256 + threadIdx.x;
    int e = (int)(gid >> SHIFT);
    if (e >= NE) return;
    int q = ((int)gid) & ((C / 4) - 1);
    int s = src[e], d = dst[e];
    float w = ew[e];
    const float4 v = *(const float4*)(feat + (size_t)s * C + q * 4);
    float* p = agg + (size_t)d * C + q * 4;
    atomicAdd(p + 0, v.x * w);
    atomicAdd(p + 1, v.y * w);
    atomicAdd(p + 2, v.z * w);
    atomicAdd(p + 3, v.w * w);
}

// C[i,:] = concat(agg[i,:]*dinv[i], self[i,:]) @ [Wl; Wr] + b, optional relu.
// 64x64 tile, 256 threads, 4x4 microtile, KB=16. Used for layer 0 (no aliasing).
__global__ __launch_bounds__(256) void k_gemm(const float* __restrict__ Aagg,
                                              const float* __restrict__ Aself,
                                              const float* __restrict__ dinv,
                                              const float* __restrict__ Wl,
                                              const float* __restrict__ Wr,
                                              const float* __restrict__ bias,
                                              float* __restrict__ out,
                                              int K0, int do_relu) {
    __shared__ float As[16][68];
    __shared__ float Bs[16][68];
    const int tid = threadIdx.x;
    const int m0 = blockIdx.x * 64;
    const int n0 = blockIdx.y * 64;
    const int tx = tid & 15, ty = tid >> 4;
    const int aq = (tid & 3) * 4;
    const int arow = tid >> 2;
    const int grow = m0 + arow;
    const bool aok = grow < NN;
    const float di = aok ? dinv[grow] : 0.0f;
    const int bj = (tid & 15) * 4;
    const int bk = tid >> 4;
    const int K = 2 * K0;

    float acc[4][4] = {};

    for (int k0 = 0; k0 < K; k0 += 16) {
        float4 av = make_float4(0.f, 0.f, 0.f, 0.f);
        if (aok) {
            int ka = k0 + aq;
            if (ka < K0) {
                av = *(const float4*)(Aagg + (size_t)grow * K0 + ka);
                av.x *= di; av.y *= di; av.z *= di; av.w *= di;
            } else {
                av = *(const float4*)(Aself + (size_t)grow * K0 + (ka - K0));
            }
        }
        int kb = k0 + bk;
        const float* wp = (kb < K0) ? (Wl + (size_t)kb * 256 + n0 + bj)
                                    : (Wr + (size_t)(kb - K0) * 256 + n0 + bj);
        float4 bv = *(const float4*)wp;

        __syncthreads();
        As[aq + 0][arow] = av.x;
        As[aq + 1][arow] = av.y;
        As[aq + 2][arow] = av.z;
        As[aq + 3][arow] = av.w;
        *(float4*)&Bs[bk][bj] = bv;
        __syncthreads();

#pragma unroll
        for (int kk = 0; kk < 16; ++kk) {
            float4 a = *(const float4*)&As[kk][ty * 4];
            float4 b = *(const float4*)&Bs[kk][tx * 4];
            acc[0][0] += a.x * b.x; acc[0][1] += a.x * b.y; acc[0][2] += a.x * b.z; acc[0][3] += a.x * b.w;
            acc[1][0] += a.y * b.x; acc[1][1] += a.y * b.y; acc[1][2] += a.y * b.z; acc[1][3] += a.y * b.w;
            acc[2][0] += a.z * b.x; acc[2][1] += a.z * b.y; acc[2][2] += a.z * b.z; acc[2][3] += a.z * b.w;
            acc[3][0] += a.w * b.x; acc[3][1] += a.w * b.y; acc[3][2] += a.w * b.z; acc[3][3] += a.w * b.w;
        }
    }

    float4 bb = *(const float4*)(bias + n0 + tx * 4);
#pragma unroll
    for (int r = 0; r < 4; ++r) {
        int row = m0 + ty * 4 + r;
        if (row < NN) {
            float4 o;
            o.x = acc[r][0] + bb.x;
            o.y = acc[r][1] + bb.y;
            o.z = acc[r][2] + bb.z;
            o.w = acc[r][3] + bb.w;
            if (do_relu) {
                o.x = fmaxf(o.x, 0.f); o.y = fmaxf(o.y, 0.f);
                o.z = fmaxf(o.z, 0.f); o.w = fmaxf(o.w, 0.f);
            }
            *(float4*)(out + (size_t)row * 256 + n0 + tx * 4) = o;
        }
    }
}

// Full-width variant: one block owns rows m0..m0+63 and ALL 256 output columns.
// Safe for in-place out = f(out, ...) since row ranges are disjoint across blocks
// and all reads precede the epilogue writes within a block.
__global__ __launch_bounds__(256) void k_gemm_full(const float* __restrict__ Aagg,
                                                   const float* __restrict__ Aself,
                                                   const float* __restrict__ dinv,
                                                   const float* __restrict__ Wl,
                                                   const float* __restrict__ Wr,
                                                   const float* __restrict__ bias,
                                                   float* __restrict__ out,
                                                   int K0, int do_relu) {
    __shared__ float As[16][68];
    __shared__ float Bs[16][260];
    const int tid = threadIdx.x;
    const int m0 = blockIdx.x * 64;
    const int tx = tid & 15;        // 16 col-groups of 16 cols
    const int ty = tid >> 4;        // 16 row-groups of 4 rows
    const int aq = (tid & 3) * 4;
    const int arow = tid >> 2;
    const int grow = m0 + arow;
    const bool aok = grow < NN;
    const float di = aok ? dinv[grow] : 0.0f;
    const int bk = tid >> 4;        // k row 0..15
    const int bj0 = (tid & 15) * 16; // col start, loads 16 cols (4 float4)
    const int K = 2 * K0;

    float acc[4][16] = {};

    for (int k0 = 0; k0 < K; k0 += 16) {
        float4 av = make_float4(0.f, 0.f, 0.f, 0.f);
        if (aok) {
            int ka = k0 + aq;
            if (ka < K0) {
                av = *(const float4*)(Aagg + (size_t)grow * K0 + ka);
                av.x *= di; av.y *= di; av.z *= di; av.w *= di;
            } else {
                av = *(const float4*)(Aself + (size_t)grow * K0 + (ka - K0));
            }
        }
        int kb = k0 + bk;
        const float* wrow = (kb < K0) ? (Wl + (size_t)kb * 256)
                                      : (Wr + (size_t)(kb - K0) * 256);
        float4 bv0 = *(const float4*)(wrow + bj0 + 0);
        float4 bv1 = *(const float4*)(wrow + bj0 + 4);
        float4 bv2 = *(const float4*)(wrow + bj0 + 8);
        float4 bv3 = *(const float4*)(wrow + bj0 + 12);

        __syncthreads();
        As[aq + 0][arow] = av.x;
        As[aq + 1][arow] = av.y;
        As[aq + 2][arow] = av.z;
        As[aq + 3][arow] = av.w;
        *(float4*)&Bs[bk][bj0 + 0]  = bv0;
        *(float4*)&Bs[bk][bj0 + 4]  = bv1;
        *(float4*)&Bs[bk][bj0 + 8]  = bv2;
        *(float4*)&Bs[bk][bj0 + 12] = bv3;
        __syncthreads();

#pragma unroll
        for (int kk = 0; kk < 16; ++kk) {
            float4 a = *(const float4*)&As[kk][ty * 4];
            float ar[4] = {a.x, a.y, a.z, a.w};
#pragma unroll
            for (int c4 = 0; c4 < 4; ++c4) {
                float4 b = *(const float4*)&Bs[kk][tx * 16 + c4 * 4];
#pragma unroll
                for (int r = 0; r < 4; ++r) {
                    acc[r][c4 * 4 + 0] += ar[r] * b.x;
                    acc[r][c4 * 4 + 1] += ar[r] * b.y;
                    acc[r][c4 * 4 + 2] += ar[r] * b.z;
                    acc[r][c4 * 4 + 3] += ar[r] * b.w;
                }
            }
        }
    }

#pragma unroll
    for (int r = 0; r < 4; ++r) {
        int row = m0 + ty * 4 + r;
        if (row < NN) {
#pragma unroll
            for (int c4 = 0; c4 < 4; ++c4) {
                float4 bb = *(const float4*)(bias + tx * 16 + c4 * 4);
                float4 o;
                o.x = acc[r][c4 * 4 + 0] + bb.x;
                o.y = acc[r][c4 * 4 + 1] + bb.y;
                o.z = acc[r][c4 * 4 + 2] + bb.z;
                o.w = acc[r][c4 * 4 + 3] + bb.w;
                if (do_relu) {
                    o.x = fmaxf(o.x, 0.f); o.y = fmaxf(o.y, 0.f);
                    o.z = fmaxf(o.z, 0.f); o.w = fmaxf(o.w, 0.f);
                }
                *(float4*)(out + (size_t)row * 256 + tx * 16 + c4 * 4) = o;
            }
        }
    }
}

extern "C" void kernel_launch(void* const* d_in, const int* in_sizes, int n_in,
                              void* d_out, int out_size, void* d_ws, size_t ws_size,
                              hipStream_t stream) {
    const float* x   = (const float*)d_in[0];
    const int*   ei  = (const int*)d_in[1];
    const float* ew  = (const float*)d_in[2];
    const float* Wl0 = (const float*)d_in[3];
    const float* Wr0 = (const float*)d_in[4];
    const float* b0  = (const float*)d_in[5];
    const float* Wl1 = (const float*)d_in[6];
    const float* Wr1 = (const float*)d_in[7];
    const float* b1  = (const float*)d_in[8];
    float* out = (float*)d_out;

    const int* src = ei;
    const int* dst = ei + NE;

    char* ws = (char*)d_ws;
    float* deg = (float*)ws;                 // 50000 floats (padded region 204800 B)
    float* agg = (float*)(ws + 204800);      // up to 50000*256 floats = 51.2 MB

    hipMemsetAsync(deg, 0, NN * sizeof(float), stream);
    hipMemsetAsync(agg, 0, (size_t)NN * C0 * sizeof(float), stream);

    k_degree<<<(NE + 255) / 256, 256, 0, stream>>>(dst, deg);
    k_deginv<<<(NN + 255) / 256, 256, 0, stream>>>(deg);

    // layer 0: aggregate x (128 ch) into agg
    {
        long long threads = (long long)NE * (C0 / 4);
        int blocks = (int)((threads + 255) / 256);
        k_scatter<C0, 5><<<blocks, 256, 0, stream>>>(x, src, dst, ew, agg);
    }
    dim3 g0((NN + 63) / 64, 4);
    // h1 = relu(concat(agg*dinv, x) @ [Wl0;Wr0] + b0) -> stored in d_out
    k_gemm<<<g0, 256, 0, stream>>>(agg, x, deg, Wl0, Wr0, b0, out, C0, 1);

    hipMemsetAsync(agg, 0, (size_t)NN * C1 * sizeof(float), stream);
    // layer 1: aggregate h1 (256 ch) into agg
    {
        long long threads = (long long)NE * (C1 / 4);
        int blocks = (int)((threads + 255) / 256);
        k_scatter<C1, 6><<<blocks, 256, 0, stream>>>(out, src, dst, ew, agg);
    }
    // out = concat(agg*dinv, h1) @ [Wl1;Wr1] + b1  (in-place, row-stripe local)
    k_gemm_full<<<(NN + 63) / 64, 256, 0, stream>>>(agg, out, deg, Wl1, Wr1, b1, out, C1, 0);
}

// Round 3
// 888.450 us; speedup vs baseline: 5.1571x; 5.1571x over previous
//
#include <hip/hip_runtime.h>

// GraphSAGE 2-layer, fp32. N=50000 nodes, E=800000 edges, 128 -> 256 -> 256.
// Round 3: replace atomic scatter (85% of runtime) with on-the-fly CSR build
// (histogram -> single-block scan -> bucket) + per-wave gather aggregation.
// agg rows are written once, pre-scaled by deg_inv.

#define NN 50000
#define NE 800000
#define C0 128
#define C1 256
#define SCAN_T 1024
#define PER 49  // ceil(50000/1024)

__global__ __launch_bounds__(256) void k_hist(const int* __restrict__ dst,
                                              int* __restrict__ cnt) {
    int e = blockIdx.x * 256 + threadIdx.x;
    if (e < NE) atomicAdd(&cnt[dst[e]], 1);
}

// Single-block exclusive scan of 50000 counts -> row_ptr + cursor + deg_inv.
__global__ __launch_bounds__(SCAN_T) void k_scan(const int* __restrict__ cnt,
                                                 int* __restrict__ row_ptr,
                                                 int* __restrict__ cursor,
                                                 float* __restrict__ dinv) {
    __shared__ int part[SCAN_T];
    const int tid = threadIdx.x;
    const int base = tid * PER;
    int local[PER];
    int s = 0;
#pragma unroll
    for (int i = 0; i < PER; ++i) {
        int idx = base + i;
        int c = (idx < NN) ? cnt[idx] : 0;
        local[i] = c;
        s += c;
    }
    part[tid] = s;
    __syncthreads();
    for (int off = 1; off < SCAN_T; off <<= 1) {
        int v = (tid >= off) ? part[tid - off] : 0;
        __syncthreads();
        part[tid] += v;
        __syncthreads();
    }
    int run = (tid > 0) ? part[tid - 1] : 0;
#pragma unroll
    for (int i = 0; i < PER; ++i) {
        int idx = base + i;
        if (idx < NN) {
            row_ptr[idx] = run;
            cursor[idx] = run;
            dinv[idx] = 1.0f / fmaxf((float)local[i], 1.0f);
            run += local[i];
        }
    }
    if (tid == 0) row_ptr[NN] = NE;
}

__global__ __launch_bounds__(256) void k_bucket(const int* __restrict__ src,
                                                const int* __restrict__ dst,
                                                const float* __restrict__ ew,
                                                int* __restrict__ cursor,
                                                int* __restrict__ es,
                                                float* __restrict__ ews) {
    int e = blockIdx.x * 256 + threadIdx.x;
    if (e >= NE) return;
    int d = dst[e];
    int pos = atomicAdd(&cursor[d], 1);
    es[pos] = src[e];
    ews[pos] = ew[e];
}

// One wave per node; lanes hold C/64 channels each. agg[i,:] = dinv[i] * sum_e w_e * feat[src_e,:]
template <int C>
__global__ __launch_bounds__(256) void k_gather(const float* __restrict__ feat,
                                                const int* __restrict__ rp,
                                                const int* __restrict__ es,
                                                const float* __restrict__ ews,
                                                const float* __restrict__ dinv,
                                                float* __restrict__ agg) {
    int wid = (blockIdx.x * 256 + threadIdx.x) >> 6;
    int lane = threadIdx.x & 63;
    if (wid >= NN) return;
    int beg = rp[wid], end = rp[wid + 1];
    float di = dinv[wid];
    if (C == 128) {
        float2 acc = {0.f, 0.f};
        for (int e = beg; e < end; ++e) {
            int s = es[e];
            float w = ews[e];
            float2 v = *(const float2*)(feat + (size_t)s * C + lane * 2);
            acc.x += w * v.x;
            acc.y += w * v.y;
        }
        acc.x *= di; acc.y *= di;
        *(float2*)(agg + (size_t)wid * C + lane * 2) = acc;
    } else {
        float4 acc = {0.f, 0.f, 0.f, 0.f};
        for (int e = beg; e < end; ++e) {
            int s = es[e];
            float w = ews[e];
            float4 v = *(const float4*)(feat + (size_t)s * C + lane * 4);
            acc.x += w * v.x;
            acc.y += w * v.y;
            acc.z += w * v.z;
            acc.w += w * v.w;
        }
        acc.x *= di; acc.y *= di; acc.z *= di; acc.w *= di;
        *(float4*)(agg + (size_t)wid * C + lane * 4) = acc;
    }
}

// C[i,:] = concat(agg[i,:], self[i,:]) @ [Wl; Wr] + b, optional relu.
// 64x64 tile, 256 threads, 4x4 microtile, KB=16. Layer 0 (no aliasing).
__global__ __launch_bounds__(256) void k_gemm(const float* __restrict__ Aagg,
                                              const float* __restrict__ Aself,
                                              const float* __restrict__ Wl,
                                              const float* __restrict__ Wr,
                                              const float* __restrict__ bias,
                                              float* __restrict__ out,
                                              int K0, int do_relu) {
    __shared__ float As[16][68];
    __shared__ float Bs[16][68];
    const int tid = threadIdx.x;
    const int m0 = blockIdx.x * 64;
    const int n0 = blockIdx.y * 64;
    const int tx = tid & 15, ty = tid >> 4;
    const int aq = (tid & 3) * 4;
    const int arow = tid >> 2;
    const int grow = m0 + arow;
    const bool aok = grow < NN;
    const int bj = (tid & 15) * 4;
    const int bk = tid >> 4;
    const int K = 2 * K0;

    float acc[4][4] = {};

    for (int k0 = 0; k0 < K; k0 += 16) {
        float4 av = make_float4(0.f, 0.f, 0.f, 0.f);
        if (aok) {
            int ka = k0 + aq;
            av = (ka < K0) ? *(const float4*)(Aagg + (size_t)grow * K0 + ka)
                           : *(const float4*)(Aself + (size_t)grow * K0 + (ka - K0));
        }
        int kb = k0 + bk;
        const float* wp = (kb < K0) ? (Wl + (size_t)kb * 256 + n0 + bj)
                                    : (Wr + (size_t)(kb - K0) * 256 + n0 + bj);
        float4 bv = *(const float4*)wp;

        __syncthreads();
        As[aq + 0][arow] = av.x;
        As[aq + 1][arow] = av.y;
        As[aq + 2][arow] = av.z;
        As[aq + 3][arow] = av.w;
        *(float4*)&Bs[bk][bj] = bv;
        __syncthreads();

#pragma unroll
        for (int kk = 0; kk < 16; ++kk) {
            float4 a = *(const float4*)&As[kk][ty * 4];
            float4 b = *(const float4*)&Bs[kk][tx * 4];
            acc[0][0] += a.x * b.x; acc[0][1] += a.x * b.y; acc[0][2] += a.x * b.z; acc[0][3] += a.x * b.w;
            acc[1][0] += a.y * b.x; acc[1][1] += a.y * b.y; acc[1][2] += a.y * b.z; acc[1][3] += a.y * b.w;
            acc[2][0] += a.z * b.x; acc[2][1] += a.z * b.y; acc[2][2] += a.z * b.z; acc[2][3] += a.z * b.w;
            acc[3][0] += a.w * b.x; acc[3][1] += a.w * b.y; acc[3][2] += a.w * b.z; acc[3][3] += a.w * b.w;
        }
    }

    float4 bb = *(const float4*)(bias + n0 + tx * 4);
#pragma unroll
    for (int r = 0; r < 4; ++r) {
        int row = m0 + ty * 4 + r;
        if (row < NN) {
            float4 o;
            o.x = acc[r][0] + bb.x;
            o.y = acc[r][1] + bb.y;
            o.z = acc[r][2] + bb.z;
            o.w = acc[r][3] + bb.w;
            if (do_relu) {
                o.x = fmaxf(o.x, 0.f); o.y = fmaxf(o.y, 0.f);
                o.z = fmaxf(o.z, 0.f); o.w = fmaxf(o.w, 0.f);
            }
            *(float4*)(out + (size_t)row * 256 + n0 + tx * 4) = o;
        }
    }
}

// Full-width variant: one block owns rows m0..m0+63 and ALL 256 output columns.
// Safe for in-place out = f(out, ...): row ranges disjoint across blocks, all
// reads precede epilogue writes within a block.
__global__ __launch_bounds__(256) void k_gemm_full(const float* __restrict__ Aagg,
                                                   const float* __restrict__ Aself,
                                                   const float* __restrict__ Wl,
                                                   const float* __restrict__ Wr,
                                                   const float* __restrict__ bias,
                                                   float* __restrict__ out,
                                                   int K0, int do_relu) {
    __shared__ float As[16][68];
    __shared__ float Bs[16][260];
    const int tid = threadIdx.x;
    const int m0 = blockIdx.x * 64;
    const int tx = tid & 15;
    const int ty = tid >> 4;
    const int aq = (tid & 3) * 4;
    const int arow = tid >> 2;
    const int grow = m0 + arow;
    const bool aok = grow < NN;
    const int bk = tid >> 4;
    const int bj0 = (tid & 15) * 16;
    const int K = 2 * K0;

    float acc[4][16] = {};

    for (int k0 = 0; k0 < K; k0 += 16) {
        float4 av = make_float4(0.f, 0.f, 0.f, 0.f);
        if (aok) {
            int ka = k0 + aq;
            av = (ka < K0) ? *(const float4*)(Aagg + (size_t)grow * K0 + ka)
                           : *(const float4*)(Aself + (size_t)grow * K0 + (ka - K0));
        }
        int kb = k0 + bk;
        const float* wrow = (kb < K0) ? (Wl + (size_t)kb * 256)
                                      : (Wr + (size_t)(kb - K0) * 256);
        float4 bv0 = *(const float4*)(wrow + bj0 + 0);
        float4 bv1 = *(const float4*)(wrow + bj0 + 4);
        float4 bv2 = *(const float4*)(wrow + bj0 + 8);
        float4 bv3 = *(const float4*)(wrow + bj0 + 12);

        __syncthreads();
        As[aq + 0][arow] = av.x;
        As[aq + 1][arow] = av.y;
        As[aq + 2][arow] = av.z;
        As[aq + 3][arow] = av.w;
        *(float4*)&Bs[bk][bj0 + 0]  = bv0;
        *(float4*)&Bs[bk][bj0 + 4]  = bv1;
        *(float4*)&Bs[bk][bj0 + 8]  = bv2;
        *(float4*)&Bs[bk][bj0 + 12] = bv3;
        __syncthreads();

#pragma unroll
        for (int kk = 0; kk < 16; ++kk) {
            float4 a = *(const float4*)&As[kk][ty * 4];
            float ar[4] = {a.x, a.y, a.z, a.w};
#pragma unroll
            for (int c4 = 0; c4 < 4; ++c4) {
                float4 b = *(const float4*)&Bs[kk][tx * 16 + c4 * 4];
#pragma unroll
                for (int r = 0; r < 4; ++r) {
                    acc[r][c4 * 4 + 0] += ar[r] * b.x;
                    acc[r][c4 * 4 + 1] += ar[r] * b.y;
                    acc[r][c4 * 4 + 2] += ar[r] * b.z;
                    acc[r][c4 * 4 + 3] += ar[r] * b.w;
                }
            }
        }
    }

#pragma unroll
    for (int r = 0; r < 4; ++r) {
        int row = m0 + ty * 4 + r;
        if (row < NN) {
#pragma unroll
            for (int c4 = 0; c4 < 4; ++c4) {
                float4 bb = *(const float4*)(bias + tx * 16 + c4 * 4);
                float4 o;
                o.x = acc[r][c4 * 4 + 0] + bb.x;
                o.y = acc[r][c4 * 4 + 1] + bb.y;
                o.z = acc[r][c4 * 4 + 2] + bb.z;
                o.w = acc[r][c4 * 4 + 3] + bb.w;
                if (do_relu) {
                    o.x = fmaxf(o.x, 0.f); o.y = fmaxf(o.y, 0.f);
                    o.z = fmaxf(o.z, 0.f); o.w = fmaxf(o.w, 0.f);
                }
                *(float4*)(out + (size_t)row * 256 + tx * 16 + c4 * 4) = o;
            }
        }
    }
}

extern "C" void kernel_launch(void* const* d_in, const int* in_sizes, int n_in,
                              void* d_out, int out_size, void* d_ws, size_t ws_size,
                              hipStream_t stream) {
    const float* x   = (const float*)d_in[0];
    const int*   ei  = (const int*)d_in[1];
    const float* ew  = (const float*)d_in[2];
    const float* Wl0 = (const float*)d_in[3];
    const float* Wr0 = (const float*)d_in[4];
    const float* b0  = (const float*)d_in[5];
    const float* Wl1 = (const float*)d_in[6];
    const float* Wr1 = (const float*)d_in[7];
    const float* b1  = (const float*)d_in[8];
    float* out = (float*)d_out;

    const int* src = ei;
    const int* dst = ei + NE;

    // ws layout (bytes):
    //   0        dinv      float[50000]   (204800)
    //   204800   cnt       int[50000]     (204800)
    //   409600   row_ptr   int[50001]     (204800)
    //   614400   cursor    int[50000]     (204800)
    //   819200   es        int[800000]    (3200000)
    //   4019200  ews       float[800000]  (3200000)
    //   7219200  agg       float[50000*256] (51200000)  -> total 58.4 MB
    char* ws = (char*)d_ws;
    float* dinv   = (float*)(ws + 0);
    int*   cnt    = (int*)(ws + 204800);
    int*   rp     = (int*)(ws + 409600);
    int*   cursor = (int*)(ws + 614400);
    int*   es     = (int*)(ws + 819200);
    float* ews    = (float*)(ws + 4019200);
    float* agg    = (float*)(ws + 7219200);

    hipMemsetAsync(cnt, 0, NN * sizeof(int), stream);
    k_hist<<<(NE + 255) / 256, 256, 0, stream>>>(dst, cnt);
    k_scan<<<1, SCAN_T, 0, stream>>>(cnt, rp, cursor, dinv);
    k_bucket<<<(NE + 255) / 256, 256, 0, stream>>>(src, dst, ew, cursor, es, ews);

    // layer 0: agg = dinv * scatter-sum(x) via gather; then h1 -> d_out
    k_gather<C0><<<(NN * 64 + 255) / 256, 256, 0, stream>>>(x, rp, es, ews, dinv, agg);
    dim3 g0((NN + 63) / 64, 4);
    k_gemm<<<g0, 256, 0, stream>>>(agg, x, Wl0, Wr0, b0, out, C0, 1);

    // layer 1: agg = dinv * scatter-sum(h1) via gather; out in-place
    k_gather<C1><<<(NN * 64 + 255) / 256, 256, 0, stream>>>(out, rp, es, ews, dinv, agg);
    k_gemm_full<<<(NN + 63) / 64, 256, 0, stream>>>(agg, out, Wl1, Wr1, b1, out, C1, 0);
}

// Round 4
// 478.570 us; speedup vs baseline: 9.5740x; 1.8565x over previous
//
#include <hip/hip_runtime.h>

// GraphSAGE 2-layer. N=50000, E=800000, 128 -> 256 -> 256.
// Round 4: bf16 MFMA GEMMs (16x16x32, 128x128 tiles, fp32 accum).
// CSR build (hist/scan/bucket) -> gather (bf16 agg) -> mfma gemm0 (bf16 h1)
// -> gather1 (bf16) -> mfma gemm1 (fp32 out).

#define NN 50000
#define NE 800000
#define SCAN_T 1024
#define PER 49  // ceil(50000/1024)

typedef __bf16 v8bf __attribute__((ext_vector_type(8)));
typedef float v4f __attribute__((ext_vector_type(4)));

__device__ __forceinline__ unsigned short f2b(float f) {
    unsigned u = __float_as_uint(f);
    return (unsigned short)((u + 0x7FFFu + ((u >> 16) & 1u)) >> 16);
}
__device__ __forceinline__ float b2f(unsigned short h) {
    return __uint_as_float(((unsigned)h) << 16);
}
__device__ __forceinline__ unsigned pack2(float a, float b) {
    return (unsigned)f2b(a) | ((unsigned)f2b(b) << 16);
}

__global__ __launch_bounds__(256) void k_hist(const int* __restrict__ dst,
                                              int* __restrict__ cnt) {
    int e = blockIdx.x * 256 + threadIdx.x;
    if (e < NE) atomicAdd(&cnt[dst[e]], 1);
}

// Single-block exclusive scan. cursor may alias cnt (read-before-write per thread).
__global__ __launch_bounds__(SCAN_T) void k_scan(const int* __restrict__ cnt,
                                                 int* __restrict__ row_ptr,
                                                 int* __restrict__ cursor,
                                                 float* __restrict__ dinv) {
    __shared__ int part[SCAN_T];
    const int tid = threadIdx.x;
    const int base = tid * PER;
    int local[PER];
    int s = 0;
#pragma unroll
    for (int i = 0; i < PER; ++i) {
        int idx = base + i;
        int c = (idx < NN) ? cnt[idx] : 0;
        local[i] = c;
        s += c;
    }
    part[tid] = s;
    __syncthreads();
    for (int off = 1; off < SCAN_T; off <<= 1) {
        int v = (tid >= off) ? part[tid - off] : 0;
        __syncthreads();
        part[tid] += v;
        __syncthreads();
    }
    int run = (tid > 0) ? part[tid - 1] : 0;
#pragma unroll
    for (int i = 0; i < PER; ++i) {
        int idx = base + i;
        if (idx < NN) {
            row_ptr[idx] = run;
            cursor[idx] = run;
            dinv[idx] = 1.0f / fmaxf((float)local[i], 1.0f);
            run += local[i];
        }
    }
    if (tid == 0) row_ptr[NN] = NE;
}

__global__ __launch_bounds__(256) void k_bucket(const int* __restrict__ src,
                                                const int* __restrict__ dst,
                                                const float* __restrict__ ew,
                                                int* __restrict__ cursor,
                                                int2* __restrict__ epk) {
    int e = blockIdx.x * 256 + threadIdx.x;
    if (e >= NE) return;
    int d = dst[e];
    int pos = atomicAdd(&cursor[d], 1);
    epk[pos] = make_int2(src[e], __float_as_int(ew[e]));
}

// Bt[n][k] (n in [0,256), k in [0,2*K0)): concat(Wl;Wr) transposed, bf16.
template <int K0>
__global__ __launch_bounds__(256) void k_wcast(const float* __restrict__ Wl,
                                               const float* __restrict__ Wr,
                                               unsigned short* __restrict__ Bt) {
    const int K = 2 * K0;
    int idx = blockIdx.x * 256 + threadIdx.x;
    if (idx >= 256 * K) return;
    int n = idx >> (K0 == 128 ? 8 : 9);
    int k = idx & (K - 1);
    float v = (k < K0) ? Wl[(size_t)k * 256 + n] : Wr[(size_t)(k - K0) * 256 + n];
    Bt[idx] = f2b(v);
}

// gather0: x fp32 [NN][128] -> aggb bf16 [NN][128] (pre-scaled by dinv). 1 wave/node.
__global__ __launch_bounds__(256) void k_gather0(const float* __restrict__ x,
                                                 const int* __restrict__ rp,
                                                 const int2* __restrict__ epk,
                                                 const float* __restrict__ dinv,
                                                 unsigned short* __restrict__ aggb) {
    int wid = (blockIdx.x * 256 + threadIdx.x) >> 6;
    int lane = threadIdx.x & 63;
    if (wid >= NN) return;
    int beg = rp[wid], end = rp[wid + 1];
    float di = dinv[wid];
    float ax = 0.f, ay = 0.f;
    int e = beg;
    for (; e + 1 < end; e += 2) {
        int2 p0 = epk[e], p1 = epk[e + 1];
        float2 v0 = *(const float2*)(x + (size_t)p0.x * 128 + lane * 2);
        float2 v1 = *(const float2*)(x + (size_t)p1.x * 128 + lane * 2);
        float w0 = __int_as_float(p0.y), w1 = __int_as_float(p1.y);
        ax += w0 * v0.x + w1 * v1.x;
        ay += w0 * v0.y + w1 * v1.y;
    }
    if (e < end) {
        int2 p = epk[e];
        float w = __int_as_float(p.y);
        float2 v = *(const float2*)(x + (size_t)p.x * 128 + lane * 2);
        ax += w * v.x; ay += w * v.y;
    }
    *(unsigned*)(aggb + (size_t)wid * 128 + lane * 2) = pack2(ax * di, ay * di);
}

// gather1: h1 bf16 [NN][256] -> aggb bf16 [NN][256]. 1 wave/node, 4 ch/lane.
__global__ __launch_bounds__(256) void k_gather1(const unsigned short* __restrict__ h,
                                                 const int* __restrict__ rp,
                                                 const int2* __restrict__ epk,
                                                 const float* __restrict__ dinv,
                                                 unsigned short* __restrict__ aggb) {
    int wid = (blockIdx.x * 256 + threadIdx.x) >> 6;
    int lane = threadIdx.x & 63;
    if (wid >= NN) return;
    int beg = rp[wid], end = rp[wid + 1];
    float di = dinv[wid];
    float a0 = 0.f, a1 = 0.f, a2 = 0.f, a3 = 0.f;
    int e = beg;
    for (; e + 1 < end; e += 2) {
        int2 p0 = epk[e], p1 = epk[e + 1];
        uint2 u0 = *(const uint2*)(h + (size_t)p0.x * 256 + lane * 4);
        uint2 u1 = *(const uint2*)(h + (size_t)p1.x * 256 + lane * 4);
        float w0 = __int_as_float(p0.y), w1 = __int_as_float(p1.y);
        a0 += w0 * b2f((unsigned short)(u0.x & 0xFFFF)) + w1 * b2f((unsigned short)(u1.x & 0xFFFF));
        a1 += w0 * b2f((unsigned short)(u0.x >> 16))    + w1 * b2f((unsigned short)(u1.x >> 16));
        a2 += w0 * b2f((unsigned short)(u0.y & 0xFFFF)) + w1 * b2f((unsigned short)(u1.y & 0xFFFF));
        a3 += w0 * b2f((unsigned short)(u0.y >> 16))    + w1 * b2f((unsigned short)(u1.y >> 16));
    }
    if (e < end) {
        int2 p = epk[e];
        float w = __int_as_float(p.y);
        uint2 u = *(const uint2*)(h + (size_t)p.x * 256 + lane * 4);
        a0 += w * b2f((unsigned short)(u.x & 0xFFFF));
        a1 += w * b2f((unsigned short)(u.x >> 16));
        a2 += w * b2f((unsigned short)(u.y & 0xFFFF));
        a3 += w * b2f((unsigned short)(u.y >> 16));
    }
    uint2 o;
    o.x = pack2(a0 * di, a1 * di);
    o.y = pack2(a2 * di, a3 * di);
    *(uint2*)(aggb + (size_t)wid * 256 + lane * 4) = o;
}

// MFMA GEMM: C[row, 0:256] = concat(Aagg[row,:], Aself[row,:]) @ Bt^T + bias.
// 128x128 tile per block, 256 threads = 4 waves (2x2), 4x4 MFMA 16x16x32 per wave.
// Aagg/Aself: [NN][K0] (bf16; Aself fp32 if SELF_F32). Bt: [256][2*K0] bf16 (n-major).
template <int K0, bool SELF_F32, bool OUT_F32, bool RELU>
__global__ __launch_bounds__(256) void k_mfma(const unsigned short* __restrict__ Aagg,
                                              const void* __restrict__ Aself,
                                              const unsigned short* __restrict__ Bt,
                                              const float* __restrict__ bias,
                                              void* __restrict__ outp) {
    __shared__ unsigned short As[128 * 32];
    __shared__ unsigned short Bs[128 * 32];
    const int tid = threadIdx.x;
    const int m0 = blockIdx.x * 128;
    const int n0 = blockIdx.y * 128;
    const int K = 2 * K0;
    const int lane = tid & 63;
    const int w = tid >> 6;
    const int wr = w >> 1, wc = w & 1;
    const int fr = lane & 15, fq = lane >> 4;
    const int srow = tid >> 2;          // 0..63
    const int schunk = (tid & 3) * 8;   // k-offset within 32 (8 bf16 = 16B)

    v4f acc[4][4];
#pragma unroll
    for (int mi = 0; mi < 4; ++mi)
#pragma unroll
        for (int ni = 0; ni < 4; ++ni)
            acc[mi][ni] = (v4f){0.f, 0.f, 0.f, 0.f};

    for (int k0 = 0; k0 < K; k0 += 32) {
        const int kk = k0 + schunk;
        const int r0 = m0 + srow, r1 = m0 + srow + 64;
        uint4 av0 = make_uint4(0, 0, 0, 0), av1 = make_uint4(0, 0, 0, 0);
        if (kk < K0) {
            if (r0 < NN) av0 = *(const uint4*)(Aagg + (size_t)r0 * K0 + kk);
            if (r1 < NN) av1 = *(const uint4*)(Aagg + (size_t)r1 * K0 + kk);
        } else {
            const int ks = kk - K0;
            if (SELF_F32) {
                const float* S = (const float*)Aself;
                if (r0 < NN) {
                    const float* p = S + (size_t)r0 * K0 + ks;
                    float4 fa = *(const float4*)p, fb = *(const float4*)(p + 4);
                    av0 = make_uint4(pack2(fa.x, fa.y), pack2(fa.z, fa.w),
                                     pack2(fb.x, fb.y), pack2(fb.z, fb.w));
                }
                if (r1 < NN) {
                    const float* p = S + (size_t)r1 * K0 + ks;
                    float4 fa = *(const float4*)p, fb = *(const float4*)(p + 4);
                    av1 = make_uint4(pack2(fa.x, fa.y), pack2(fa.z, fa.w),
                                     pack2(fb.x, fb.y), pack2(fb.z, fb.w));
                }
            } else {
                const unsigned short* S = (const unsigned short*)Aself;
                if (r0 < NN) av0 = *(const uint4*)(S + (size_t)r0 * K0 + ks);
                if (r1 < NN) av1 = *(const uint4*)(S + (size_t)r1 * K0 + ks);
            }
        }
        uint4 bv0 = *(const uint4*)(Bt + (size_t)(n0 + srow) * K + kk);
        uint4 bv1 = *(const uint4*)(Bt + (size_t)(n0 + srow + 64) * K + kk);

        __syncthreads();
        *(uint4*)(As + srow * 32 + schunk) = av0;
        *(uint4*)(As + (srow + 64) * 32 + schunk) = av1;
        *(uint4*)(Bs + srow * 32 + schunk) = bv0;
        *(uint4*)(Bs + (srow + 64) * 32 + schunk) = bv1;
        __syncthreads();

        v8bf a[4], b[4];
#pragma unroll
        for (int mi = 0; mi < 4; ++mi)
            a[mi] = *(const v8bf*)(As + (wr * 64 + mi * 16 + fr) * 32 + fq * 8);
#pragma unroll
        for (int ni = 0; ni < 4; ++ni)
            b[ni] = *(const v8bf*)(Bs + (wc * 64 + ni * 16 + fr) * 32 + fq * 8);
#pragma unroll
        for (int mi = 0; mi < 4; ++mi)
#pragma unroll
            for (int ni = 0; ni < 4; ++ni)
                acc[mi][ni] = __builtin_amdgcn_mfma_f32_16x16x32_bf16(a[mi], b[ni], acc[mi][ni], 0, 0, 0);
    }

#pragma unroll
    for (int mi = 0; mi < 4; ++mi) {
#pragma unroll
        for (int ni = 0; ni < 4; ++ni) {
            const int col = n0 + wc * 64 + ni * 16 + fr;
            const float bb = bias[col];
#pragma unroll
            for (int r = 0; r < 4; ++r) {
                const int row = m0 + wr * 64 + mi * 16 + fq * 4 + r;
                if (row < NN) {
                    float v = acc[mi][ni][r] + bb;
                    if (RELU) v = fmaxf(v, 0.f);
                    if (OUT_F32) ((float*)outp)[(size_t)row * 256 + col] = v;
                    else ((unsigned short*)outp)[(size_t)row * 256 + col] = f2b(v);
                }
            }
        }
    }
}

extern "C" void kernel_launch(void* const* d_in, const int* in_sizes, int n_in,
                              void* d_out, int out_size, void* d_ws, size_t ws_size,
                              hipStream_t stream) {
    const float* x   = (const float*)d_in[0];
    const int*   ei  = (const int*)d_in[1];
    const float* ew  = (const float*)d_in[2];
    const float* Wl0 = (const float*)d_in[3];
    const float* Wr0 = (const float*)d_in[4];
    const float* b0  = (const float*)d_in[5];
    const float* Wl1 = (const float*)d_in[6];
    const float* Wr1 = (const float*)d_in[7];
    const float* b1  = (const float*)d_in[8];
    float* out = (float*)d_out;

    const int* src = ei;
    const int* dst = ei + NE;

    // ws layout (bytes), total ~58.6 MB:
    //   0        dinv  f32[50000]        (204800)
    //   204800   cnt / cursor int[50000] (204800)  (scan aliases cursor onto cnt)
    //   409600   rp    int[50001]        (204800)
    //   614400   epk   int2[800000]      (6400000)
    //   7014400  Bt0   bf16[256*256]     (131072)
    //   7145472  Bt1   bf16[256*512]     (262144)
    //   7407616  h1b   bf16[50000*256]   (25600000)
    //   33007616 aggb  bf16[50000*256]   (25600000)  [used as [NN][128] in layer 0]
    char* ws = (char*)d_ws;
    float*          dinv = (float*)(ws + 0);
    int*            cnt  = (int*)(ws + 204800);
    int*            rp   = (int*)(ws + 409600);
    int2*           epk  = (int2*)(ws + 614400);
    unsigned short* Bt0  = (unsigned short*)(ws + 7014400);
    unsigned short* Bt1  = (unsigned short*)(ws + 7145472);
    unsigned short* h1b  = (unsigned short*)(ws + 7407616);
    unsigned short* aggb = (unsigned short*)(ws + 33007616);

    hipMemsetAsync(cnt, 0, NN * sizeof(int), stream);
    k_hist<<<(NE + 255) / 256, 256, 0, stream>>>(dst, cnt);
    k_scan<<<1, SCAN_T, 0, stream>>>(cnt, rp, /*cursor=*/cnt, dinv);
    k_bucket<<<(NE + 255) / 256, 256, 0, stream>>>(src, dst, ew, cnt, epk);

    k_wcast<128><<<(256 * 256 + 255) / 256, 256, 0, stream>>>(Wl0, Wr0, Bt0);
    k_wcast<256><<<(256 * 512 + 255) / 256, 256, 0, stream>>>(Wl1, Wr1, Bt1);

    // layer 0
    k_gather0<<<(NN * 64 + 255) / 256, 256, 0, stream>>>(x, rp, epk, dinv, aggb);
    dim3 g((NN + 127) / 128, 2);
    k_mfma<128, true, false, true><<<g, 256, 0, stream>>>(aggb, x, Bt0, b0, h1b);

    // layer 1
    k_gather1<<<(NN * 64 + 255) / 256, 256, 0, stream>>>(h1b, rp, epk, dinv, aggb);
    k_mfma<256, false, true, false><<<g, 256, 0, stream>>>(aggb, h1b, Bt1, b1, out);
}

// Round 5
// 376.428 us; speedup vs baseline: 12.1719x; 1.2713x over previous
//
#include <hip/hip_runtime.h>

// GraphSAGE 2-layer. N=50000, E=800000, 128 -> 256 -> 256.
// Round 5: replace single-block scan (107us on 1 CU) with 3-phase device-wide
// scan (~<10us). Rest identical to round 4 (bf16 MFMA GEMMs, CSR gather).

#define NN 50000
#define NE 800000
#define SB 1024
#define NB 49  // ceil(50000/1024)

typedef __bf16 v8bf __attribute__((ext_vector_type(8)));
typedef float v4f __attribute__((ext_vector_type(4)));

__device__ __forceinline__ unsigned short f2b(float f) {
    unsigned u = __float_as_uint(f);
    return (unsigned short)((u + 0x7FFFu + ((u >> 16) & 1u)) >> 16);
}
__device__ __forceinline__ float b2f(unsigned short h) {
    return __uint_as_float(((unsigned)h) << 16);
}
__device__ __forceinline__ unsigned pack2(float a, float b) {
    return (unsigned)f2b(a) | ((unsigned)f2b(b) << 16);
}

__global__ __launch_bounds__(256) void k_hist(const int* __restrict__ dst,
                                              int* __restrict__ cnt) {
    int e = blockIdx.x * 256 + threadIdx.x;
    if (e < NE) atomicAdd(&cnt[dst[e]], 1);
}

// Phase 1: per-block exclusive scan of 1024 counts -> pre, block sum -> bsum, dinv.
__global__ __launch_bounds__(SB) void k_scan1(const int* __restrict__ cnt,
                                              int* __restrict__ pre,
                                              int* __restrict__ bsum,
                                              float* __restrict__ dinv) {
    __shared__ int tmp[SB];
    const int tid = threadIdx.x;
    const int gid = blockIdx.x * SB + tid;
    int v = (gid < NN) ? cnt[gid] : 0;
    tmp[tid] = v;
    __syncthreads();
    for (int off = 1; off < SB; off <<= 1) {
        int t = (tid >= off) ? tmp[tid - off] : 0;
        __syncthreads();
        tmp[tid] += t;
        __syncthreads();
    }
    if (gid < NN) {
        pre[gid] = tmp[tid] - v;  // exclusive within block
        dinv[gid] = 1.0f / fmaxf((float)v, 1.0f);
    }
    if (tid == SB - 1) bsum[blockIdx.x] = tmp[tid];
}

// Phase 2: one wave scans NB block sums -> exclusive block offsets.
__global__ __launch_bounds__(64) void k_scan2(const int* __restrict__ bsum,
                                              int* __restrict__ boff) {
    int lane = threadIdx.x;
    int orig = (lane < NB) ? bsum[lane] : 0;
    int v = orig;
    for (int off = 1; off < 64; off <<= 1) {
        int t = __shfl_up(v, off);
        if (lane >= off) v += t;
    }
    if (lane < NB) boff[lane] = v - orig;
}

// Phase 3: add block offsets -> row_ptr + cursor.
__global__ __launch_bounds__(SB) void k_scan3(const int* __restrict__ pre,
                                              const int* __restrict__ boff,
                                              int* __restrict__ rp,
                                              int* __restrict__ cursor) {
    const int gid = blockIdx.x * SB + threadIdx.x;
    if (gid < NN) {
        int r = pre[gid] + boff[blockIdx.x];
        rp[gid] = r;
        cursor[gid] = r;
    }
    if (gid == 0) rp[NN] = NE;
}

__global__ __launch_bounds__(256) void k_bucket(const int* __restrict__ src,
                                                const int* __restrict__ dst,
                                                const float* __restrict__ ew,
                                                int* __restrict__ cursor,
                                                int2* __restrict__ epk) {
    int e = blockIdx.x * 256 + threadIdx.x;
    if (e >= NE) return;
    int d = dst[e];
    int pos = atomicAdd(&cursor[d], 1);
    epk[pos] = make_int2(src[e], __float_as_int(ew[e]));
}

// Bt[n][k]: concat(Wl;Wr) transposed, bf16.
template <int K0>
__global__ __launch_bounds__(256) void k_wcast(const float* __restrict__ Wl,
                                               const float* __restrict__ Wr,
                                               unsigned short* __restrict__ Bt) {
    const int K = 2 * K0;
    int idx = blockIdx.x * 256 + threadIdx.x;
    if (idx >= 256 * K) return;
    int n = idx >> (K0 == 128 ? 8 : 9);
    int k = idx & (K - 1);
    float v = (k < K0) ? Wl[(size_t)k * 256 + n] : Wr[(size_t)(k - K0) * 256 + n];
    Bt[idx] = f2b(v);
}

// gather0: x fp32 [NN][128] -> aggb bf16 [NN][128] (pre-scaled by dinv). 1 wave/node.
__global__ __launch_bounds__(256) void k_gather0(const float* __restrict__ x,
                                                 const int* __restrict__ rp,
                                                 const int2* __restrict__ epk,
                                                 const float* __restrict__ dinv,
                                                 unsigned short* __restrict__ aggb) {
    int wid = (blockIdx.x * 256 + threadIdx.x) >> 6;
    int lane = threadIdx.x & 63;
    if (wid >= NN) return;
    int beg = rp[wid], end = rp[wid + 1];
    float di = dinv[wid];
    float ax = 0.f, ay = 0.f;
    int e = beg;
    for (; e + 1 < end; e += 2) {
        int2 p0 = epk[e], p1 = epk[e + 1];
        float2 v0 = *(const float2*)(x + (size_t)p0.x * 128 + lane * 2);
        float2 v1 = *(const float2*)(x + (size_t)p1.x * 128 + lane * 2);
        float w0 = __int_as_float(p0.y), w1 = __int_as_float(p1.y);
        ax += w0 * v0.x + w1 * v1.x;
        ay += w0 * v0.y + w1 * v1.y;
    }
    if (e < end) {
        int2 p = epk[e];
        float w = __int_as_float(p.y);
        float2 v = *(const float2*)(x + (size_t)p.x * 128 + lane * 2);
        ax += w * v.x; ay += w * v.y;
    }
    *(unsigned*)(aggb + (size_t)wid * 128 + lane * 2) = pack2(ax * di, ay * di);
}

// gather1: h1 bf16 [NN][256] -> aggb bf16 [NN][256]. 1 wave/node, 4 ch/lane.
__global__ __launch_bounds__(256) void k_gather1(const unsigned short* __restrict__ h,
                                                 const int* __restrict__ rp,
                                                 const int2* __restrict__ epk,
                                                 const float* __restrict__ dinv,
                                                 unsigned short* __restrict__ aggb) {
    int wid = (blockIdx.x * 256 + threadIdx.x) >> 6;
    int lane = threadIdx.x & 63;
    if (wid >= NN) return;
    int beg = rp[wid], end = rp[wid + 1];
    float di = dinv[wid];
    float a0 = 0.f, a1 = 0.f, a2 = 0.f, a3 = 0.f;
    int e = beg;
    for (; e + 1 < end; e += 2) {
        int2 p0 = epk[e], p1 = epk[e + 1];
        uint2 u0 = *(const uint2*)(h + (size_t)p0.x * 256 + lane * 4);
        uint2 u1 = *(const uint2*)(h + (size_t)p1.x * 256 + lane * 4);
        float w0 = __int_as_float(p0.y), w1 = __int_as_float(p1.y);
        a0 += w0 * b2f((unsigned short)(u0.x & 0xFFFF)) + w1 * b2f((unsigned short)(u1.x & 0xFFFF));
        a1 += w0 * b2f((unsigned short)(u0.x >> 16))    + w1 * b2f((unsigned short)(u1.x >> 16));
        a2 += w0 * b2f((unsigned short)(u0.y & 0xFFFF)) + w1 * b2f((unsigned short)(u1.y & 0xFFFF));
        a3 += w0 * b2f((unsigned short)(u0.y >> 16))    + w1 * b2f((unsigned short)(u1.y >> 16));
    }
    if (e < end) {
        int2 p = epk[e];
        float w = __int_as_float(p.y);
        uint2 u = *(const uint2*)(h + (size_t)p.x * 256 + lane * 4);
        a0 += w * b2f((unsigned short)(u.x & 0xFFFF));
        a1 += w * b2f((unsigned short)(u.x >> 16));
        a2 += w * b2f((unsigned short)(u.y & 0xFFFF));
        a3 += w * b2f((unsigned short)(u.y >> 16));
    }
    uint2 o;
    o.x = pack2(a0 * di, a1 * di);
    o.y = pack2(a2 * di, a3 * di);
    *(uint2*)(aggb + (size_t)wid * 256 + lane * 4) = o;
}

// MFMA GEMM: C[row, 0:256] = concat(Aagg[row,:], Aself[row,:]) @ Bt^T + bias.
// 128x128 tile per block, 4 waves (2x2), 4x4 MFMA 16x16x32 per wave.
template <int K0, bool SELF_F32, bool OUT_F32, bool RELU>
__global__ __launch_bounds__(256) void k_mfma(const unsigned short* __restrict__ Aagg,
                                              const void* __restrict__ Aself,
                                              const unsigned short* __restrict__ Bt,
                                              const float* __restrict__ bias,
                                              void* __restrict__ outp) {
    __shared__ unsigned short As[128 * 32];
    __shared__ unsigned short Bs[128 * 32];
    const int tid = threadIdx.x;
    const int m0 = blockIdx.x * 128;
    const int n0 = blockIdx.y * 128;
    const int K = 2 * K0;
    const int lane = tid & 63;
    const int w = tid >> 6;
    const int wr = w >> 1, wc = w & 1;
    const int fr = lane & 15, fq = lane >> 4;
    const int srow = tid >> 2;
    const int schunk = (tid & 3) * 8;

    v4f acc[4][4];
#pragma unroll
    for (int mi = 0; mi < 4; ++mi)
#pragma unroll
        for (int ni = 0; ni < 4; ++ni)
            acc[mi][ni] = (v4f){0.f, 0.f, 0.f, 0.f};

    for (int k0 = 0; k0 < K; k0 += 32) {
        const int kk = k0 + schunk;
        const int r0 = m0 + srow, r1 = m0 + srow + 64;
        uint4 av0 = make_uint4(0, 0, 0, 0), av1 = make_uint4(0, 0, 0, 0);
        if (kk < K0) {
            if (r0 < NN) av0 = *(const uint4*)(Aagg + (size_t)r0 * K0 + kk);
            if (r1 < NN) av1 = *(const uint4*)(Aagg + (size_t)r1 * K0 + kk);
        } else {
            const int ks = kk - K0;
            if (SELF_F32) {
                const float* S = (const float*)Aself;
                if (r0 < NN) {
                    const float* p = S + (size_t)r0 * K0 + ks;
                    float4 fa = *(const float4*)p, fb = *(const float4*)(p + 4);
                    av0 = make_uint4(pack2(fa.x, fa.y), pack2(fa.z, fa.w),
                                     pack2(fb.x, fb.y), pack2(fb.z, fb.w));
                }
                if (r1 < NN) {
                    const float* p = S + (size_t)r1 * K0 + ks;
                    float4 fa = *(const float4*)p, fb = *(const float4*)(p + 4);
                    av1 = make_uint4(pack2(fa.x, fa.y), pack2(fa.z, fa.w),
                                     pack2(fb.x, fb.y), pack2(fb.z, fb.w));
                }
            } else {
                const unsigned short* S = (const unsigned short*)Aself;
                if (r0 < NN) av0 = *(const uint4*)(S + (size_t)r0 * K0 + ks);
                if (r1 < NN) av1 = *(const uint4*)(S + (size_t)r1 * K0 + ks);
            }
        }
        uint4 bv0 = *(const uint4*)(Bt + (size_t)(n0 + srow) * K + kk);
        uint4 bv1 = *(const uint4*)(Bt + (size_t)(n0 + srow + 64) * K + kk);

        __syncthreads();
        *(uint4*)(As + srow * 32 + schunk) = av0;
        *(uint4*)(As + (srow + 64) * 32 + schunk) = av1;
        *(uint4*)(Bs + srow * 32 + schunk) = bv0;
        *(uint4*)(Bs + (srow + 64) * 32 + schunk) = bv1;
        __syncthreads();

        v8bf a[4], b[4];
#pragma unroll
        for (int mi = 0; mi < 4; ++mi)
            a[mi] = *(const v8bf*)(As + (wr * 64 + mi * 16 + fr) * 32 + fq * 8);
#pragma unroll
        for (int ni = 0; ni < 4; ++ni)
            b[ni] = *(const v8bf*)(Bs + (wc * 64 + ni * 16 + fr) * 32 + fq * 8);
#pragma unroll
        for (int mi = 0; mi < 4; ++mi)
#pragma unroll
            for (int ni = 0; ni < 4; ++ni)
                acc[mi][ni] = __builtin_amdgcn_mfma_f32_16x16x32_bf16(a[mi], b[ni], acc[mi][ni], 0, 0, 0);
    }

#pragma unroll
    for (int mi = 0; mi < 4; ++mi) {
#pragma unroll
        for (int ni = 0; ni < 4; ++ni) {
            const int col = n0 + wc * 64 + ni * 16 + fr;
            const float bb = bias[col];
#pragma unroll
            for (int r = 0; r < 4; ++r) {
                const int row = m0 + wr * 64 + mi * 16 + fq * 4 + r;
                if (row < NN) {
                    float v = acc[mi][ni][r] + bb;
                    if (RELU) v = fmaxf(v, 0.f);
                    if (OUT_F32) ((float*)outp)[(size_t)row * 256 + col] = v;
                    else ((unsigned short*)outp)[(size_t)row * 256 + col] = f2b(v);
                }
            }
        }
    }
}

extern "C" void kernel_launch(void* const* d_in, const int* in_sizes, int n_in,
                              void* d_out, int out_size, void* d_ws, size_t ws_size,
                              hipStream_t stream) {
    const float* x   = (const float*)d_in[0];
    const int*   ei  = (const int*)d_in[1];
    const float* ew  = (const float*)d_in[2];
    const float* Wl0 = (const float*)d_in[3];
    const float* Wr0 = (const float*)d_in[4];
    const float* b0  = (const float*)d_in[5];
    const float* Wl1 = (const float*)d_in[6];
    const float* Wr1 = (const float*)d_in[7];
    const float* b1  = (const float*)d_in[8];
    float* out = (float*)d_out;

    const int* src = ei;
    const int* dst = ei + NE;

    // ws layout (bytes), total ~58.6 MB (same footprint as round 4):
    //   0        dinv  f32[50000]        (204800)
    //   204800   cnt   int[50000]; cursor aliases cnt; bsum@cnt+50048, boff@cnt+50112
    //   409600   rp    int[50001]        (204800)
    //   614400   epk   int2[800000]      (6400000)   [pre int[50176] aliases head, dead before bucket]
    //   7014400  Bt0   bf16[256*256]     (131072)
    //   7145472  Bt1   bf16[256*512]     (262144)
    //   7407616  h1b   bf16[50000*256]   (25600000)
    //   33007616 aggb  bf16[50000*256]   (25600000)
    char* ws = (char*)d_ws;
    float*          dinv = (float*)(ws + 0);
    int*            cnt  = (int*)(ws + 204800);
    int*            bsum = cnt + 50048;
    int*            boff = cnt + 50112;
    int*            rp   = (int*)(ws + 409600);
    int*            pre  = (int*)(ws + 614400);
    int2*           epk  = (int2*)(ws + 614400);
    unsigned short* Bt0  = (unsigned short*)(ws + 7014400);
    unsigned short* Bt1  = (unsigned short*)(ws + 7145472);
    unsigned short* h1b  = (unsigned short*)(ws + 7407616);
    unsigned short* aggb = (unsigned short*)(ws + 33007616);

    hipMemsetAsync(cnt, 0, NN * sizeof(int), stream);
    k_hist<<<(NE + 255) / 256, 256, 0, stream>>>(dst, cnt);
    k_scan1<<<NB, SB, 0, stream>>>(cnt, pre, bsum, dinv);
    k_scan2<<<1, 64, 0, stream>>>(bsum, boff);
    k_scan3<<<NB, SB, 0, stream>>>(pre, boff, rp, /*cursor=*/cnt);
    k_bucket<<<(NE + 255) / 256, 256, 0, stream>>>(src, dst, ew, cnt, epk);

    k_wcast<128><<<(256 * 256 + 255) / 256, 256, 0, stream>>>(Wl0, Wr0, Bt0);
    k_wcast<256><<<(256 * 512 + 255) / 256, 256, 0, stream>>>(Wl1, Wr1, Bt1);

    // layer 0
    k_gather0<<<(NN * 64 + 255) / 256, 256, 0, stream>>>(x, rp, epk, dinv, aggb);
    dim3 g((NN + 127) / 128, 2);
    k_mfma<128, true, false, true><<<g, 256, 0, stream>>>(aggb, x, Bt0, b0, h1b);

    // layer 1
    k_gather1<<<(NN * 64 + 255) / 256, 256, 0, stream>>>(h1b, rp, epk, dinv, aggb);
    k_mfma<256, false, true, false><<<g, 256, 0, stream>>>(aggb, h1b, Bt1, b1, out);
}

// Round 6
// 349.723 us; speedup vs baseline: 13.1013x; 1.0764x over previous
//
#include <hip/hip_runtime.h>

// GraphSAGE 2-layer. N=50000, E=800000, 128 -> 256 -> 256.
// Round 6: (a) pre-cast x to bf16 so gather0 reads 256B rows (halves its
// traffic), (b) fuse memset+wcast0+wcast1+xcast into one k_prep dispatch and
// scan2 into scan3 (12 -> 9 dispatches), (c) unroll gather loops x4.

#define NN 50000
#define NE 800000
#define SB 1024
#define NB 49  // ceil(50000/1024)

typedef __bf16 v8bf __attribute__((ext_vector_type(8)));
typedef float v4f __attribute__((ext_vector_type(4)));

__device__ __forceinline__ unsigned short f2b(float f) {
    unsigned u = __float_as_uint(f);
    return (unsigned short)((u + 0x7FFFu + ((u >> 16) & 1u)) >> 16);
}
__device__ __forceinline__ float b2f(unsigned short h) {
    return __uint_as_float(((unsigned)h) << 16);
}
__device__ __forceinline__ unsigned pack2(float a, float b) {
    return (unsigned)f2b(a) | ((unsigned)f2b(b) << 16);
}

// Fused prep: zero cnt | Bt0 | Bt1 | x->bf16. Sections by blockIdx.
#define PB_CNT 196    // 50176 threads
#define PB_BT0 256    // 65536
#define PB_BT1 512    // 131072
#define PB_XB  6250   // 1.6M float4
__global__ __launch_bounds__(256) void k_prep(const float* __restrict__ x,
                                              const float* __restrict__ Wl0,
                                              const float* __restrict__ Wr0,
                                              const float* __restrict__ Wl1,
                                              const float* __restrict__ Wr1,
                                              int* __restrict__ cnt,
                                              unsigned short* __restrict__ Bt0,
                                              unsigned short* __restrict__ Bt1,
                                              unsigned short* __restrict__ xb) {
    int b = blockIdx.x;
    int tid = threadIdx.x;
    if (b < PB_CNT) {
        int i = b * 256 + tid;
        if (i < NN) cnt[i] = 0;
    } else if (b < PB_CNT + PB_BT0) {
        int idx = (b - PB_CNT) * 256 + tid;             // [0, 65536)
        int n = idx >> 8, k = idx & 255;
        float v = (k < 128) ? Wl0[(size_t)k * 256 + n] : Wr0[(size_t)(k - 128) * 256 + n];
        Bt0[idx] = f2b(v);
    } else if (b < PB_CNT + PB_BT0 + PB_BT1) {
        int idx = (b - PB_CNT - PB_BT0) * 256 + tid;    // [0, 131072)
        int n = idx >> 9, k = idx & 511;
        float v = (k < 256) ? Wl1[(size_t)k * 256 + n] : Wr1[(size_t)(k - 256) * 256 + n];
        Bt1[idx] = f2b(v);
    } else {
        int i4 = (b - PB_CNT - PB_BT0 - PB_BT1) * 256 + tid;  // [0, 1.6M)
        float4 v = ((const float4*)x)[i4];
        uint2 o;
        o.x = pack2(v.x, v.y);
        o.y = pack2(v.z, v.w);
        ((uint2*)xb)[i4] = o;
    }
}

__global__ __launch_bounds__(256) void k_hist(const int* __restrict__ dst,
                                              int* __restrict__ cnt) {
    int e = blockIdx.x * 256 + threadIdx.x;
    if (e < NE) atomicAdd(&cnt[dst[e]], 1);
}

// Phase 1: per-block scan -> pre (block-exclusive), bsum, dinv.
__global__ __launch_bounds__(SB) void k_scan1(const int* __restrict__ cnt,
                                              int* __restrict__ pre,
                                              int* __restrict__ bsum,
                                              float* __restrict__ dinv) {
    __shared__ int tmp[SB];
    const int tid = threadIdx.x;
    const int gid = blockIdx.x * SB + tid;
    int v = (gid < NN) ? cnt[gid] : 0;
    tmp[tid] = v;
    __syncthreads();
    for (int off = 1; off < SB; off <<= 1) {
        int t = (tid >= off) ? tmp[tid - off] : 0;
        __syncthreads();
        tmp[tid] += t;
        __syncthreads();
    }
    if (gid < NN) {
        pre[gid] = tmp[tid] - v;
        dinv[gid] = 1.0f / fmaxf((float)v, 1.0f);
    }
    if (tid == SB - 1) bsum[blockIdx.x] = tmp[tid];
}

// Phase 2+3 fused: wave 0 scans the NB block sums; all threads add the
// block offset -> row_ptr + cursor.
__global__ __launch_bounds__(SB) void k_scan3f(const int* __restrict__ pre,
                                               const int* __restrict__ bsum,
                                               int* __restrict__ rp,
                                               int* __restrict__ cursor) {
    __shared__ int s_off;
    const int tid = threadIdx.x;
    if (tid < 64) {
        int orig = (tid < NB) ? bsum[tid] : 0;
        int v = orig;
        for (int off = 1; off < 64; off <<= 1) {
            int t = __shfl_up(v, off);
            if (tid >= off) v += t;
        }
        if (tid == (int)blockIdx.x) s_off = v - orig;  // exclusive prefix
    }
    __syncthreads();
    const int gid = blockIdx.x * SB + tid;
    if (gid < NN) {
        int r = pre[gid] + s_off;
        rp[gid] = r;
        cursor[gid] = r;
    }
    if (gid == 0) rp[NN] = NE;
}

__global__ __launch_bounds__(256) void k_bucket(const int* __restrict__ src,
                                                const int* __restrict__ dst,
                                                const float* __restrict__ ew,
                                                int* __restrict__ cursor,
                                                int2* __restrict__ epk) {
    int e = blockIdx.x * 256 + threadIdx.x;
    if (e >= NE) return;
    int d = dst[e];
    int pos = atomicAdd(&cursor[d], 1);
    epk[pos] = make_int2(src[e], __float_as_int(ew[e]));
}

// gather0: xb bf16 [NN][128] -> aggb bf16 [NN][128] (pre-scaled by dinv). 1 wave/node.
__global__ __launch_bounds__(256) void k_gather0(const unsigned short* __restrict__ xb,
                                                 const int* __restrict__ rp,
                                                 const int2* __restrict__ epk,
                                                 const float* __restrict__ dinv,
                                                 unsigned short* __restrict__ aggb) {
    int wid = (blockIdx.x * 256 + threadIdx.x) >> 6;
    int lane = threadIdx.x & 63;
    if (wid >= NN) return;
    int beg = rp[wid], end = rp[wid + 1];
    float di = dinv[wid];
    float ax = 0.f, ay = 0.f;
    int e = beg;
    for (; e + 3 < end; e += 4) {
        int2 p0 = epk[e], p1 = epk[e + 1], p2 = epk[e + 2], p3 = epk[e + 3];
        unsigned u0 = *(const unsigned*)(xb + (size_t)p0.x * 128 + lane * 2);
        unsigned u1 = *(const unsigned*)(xb + (size_t)p1.x * 128 + lane * 2);
        unsigned u2 = *(const unsigned*)(xb + (size_t)p2.x * 128 + lane * 2);
        unsigned u3 = *(const unsigned*)(xb + (size_t)p3.x * 128 + lane * 2);
        float w0 = __int_as_float(p0.y), w1 = __int_as_float(p1.y);
        float w2 = __int_as_float(p2.y), w3 = __int_as_float(p3.y);
        ax += w0 * b2f((unsigned short)(u0 & 0xFFFF)) + w1 * b2f((unsigned short)(u1 & 0xFFFF))
            + w2 * b2f((unsigned short)(u2 & 0xFFFF)) + w3 * b2f((unsigned short)(u3 & 0xFFFF));
        ay += w0 * b2f((unsigned short)(u0 >> 16)) + w1 * b2f((unsigned short)(u1 >> 16))
            + w2 * b2f((unsigned short)(u2 >> 16)) + w3 * b2f((unsigned short)(u3 >> 16));
    }
    for (; e < end; ++e) {
        int2 p = epk[e];
        float w = __int_as_float(p.y);
        unsigned u = *(const unsigned*)(xb + (size_t)p.x * 128 + lane * 2);
        ax += w * b2f((unsigned short)(u & 0xFFFF));
        ay += w * b2f((unsigned short)(u >> 16));
    }
    *(unsigned*)(aggb + (size_t)wid * 128 + lane * 2) = pack2(ax * di, ay * di);
}

// gather1: h1 bf16 [NN][256] -> aggb bf16 [NN][256]. 1 wave/node, 4 ch/lane.
__global__ __launch_bounds__(256) void k_gather1(const unsigned short* __restrict__ h,
                                                 const int* __restrict__ rp,
                                                 const int2* __restrict__ epk,
                                                 const float* __restrict__ dinv,
                                                 unsigned short* __restrict__ aggb) {
    int wid = (blockIdx.x * 256 + threadIdx.x) >> 6;
    int lane = threadIdx.x & 63;
    if (wid >= NN) return;
    int beg = rp[wid], end = rp[wid + 1];
    float di = dinv[wid];
    float a0 = 0.f, a1 = 0.f, a2 = 0.f, a3 = 0.f;
    int e = beg;
    for (; e + 3 < end; e += 4) {
        int2 p0 = epk[e], p1 = epk[e + 1], p2 = epk[e + 2], p3 = epk[e + 3];
        uint2 u0 = *(const uint2*)(h + (size_t)p0.x * 256 + lane * 4);
        uint2 u1 = *(const uint2*)(h + (size_t)p1.x * 256 + lane * 4);
        uint2 u2 = *(const uint2*)(h + (size_t)p2.x * 256 + lane * 4);
        uint2 u3 = *(const uint2*)(h + (size_t)p3.x * 256 + lane * 4);
        float w0 = __int_as_float(p0.y), w1 = __int_as_float(p1.y);
        float w2 = __int_as_float(p2.y), w3 = __int_as_float(p3.y);
        a0 += w0 * b2f((unsigned short)(u0.x & 0xFFFF)) + w1 * b2f((unsigned short)(u1.x & 0xFFFF))
            + w2 * b2f((unsigned short)(u2.x & 0xFFFF)) + w3 * b2f((unsigned short)(u3.x & 0xFFFF));
        a1 += w0 * b2f((unsigned short)(u0.x >> 16)) + w1 * b2f((unsigned short)(u1.x >> 16))
            + w2 * b2f((unsigned short)(u2.x >> 16)) + w3 * b2f((unsigned short)(u3.x >> 16));
        a2 += w0 * b2f((unsigned short)(u0.y & 0xFFFF)) + w1 * b2f((unsigned short)(u1.y & 0xFFFF))
            + w2 * b2f((unsigned short)(u2.y & 0xFFFF)) + w3 * b2f((unsigned short)(u3.y & 0xFFFF));
        a3 += w0 * b2f((unsigned short)(u0.y >> 16)) + w1 * b2f((unsigned short)(u1.y >> 16))
            + w2 * b2f((unsigned short)(u2.y >> 16)) + w3 * b2f((unsigned short)(u3.y >> 16));
    }
    for (; e < end; ++e) {
        int2 p = epk[e];
        float w = __int_as_float(p.y);
        uint2 u = *(const uint2*)(h + (size_t)p.x * 256 + lane * 4);
        a0 += w * b2f((unsigned short)(u.x & 0xFFFF));
        a1 += w * b2f((unsigned short)(u.x >> 16));
        a2 += w * b2f((unsigned short)(u.y & 0xFFFF));
        a3 += w * b2f((unsigned short)(u.y >> 16));
    }
    uint2 o;
    o.x = pack2(a0 * di, a1 * di);
    o.y = pack2(a2 * di, a3 * di);
    *(uint2*)(aggb + (size_t)wid * 256 + lane * 4) = o;
}

// MFMA GEMM: C[row, 0:256] = concat(Aagg[row,:], Aself[row,:]) @ Bt^T + bias.
// 128x128 tile per block, 4 waves (2x2), 4x4 MFMA 16x16x32 per wave. All bf16 inputs.
template <int K0, bool OUT_F32, bool RELU>
__global__ __launch_bounds__(256) void k_mfma(const unsigned short* __restrict__ Aagg,
                                              const unsigned short* __restrict__ Aself,
                                              const unsigned short* __restrict__ Bt,
                                              const float* __restrict__ bias,
                                              void* __restrict__ outp) {
    __shared__ unsigned short As[128 * 32];
    __shared__ unsigned short Bs[128 * 32];
    const int tid = threadIdx.x;
    const int m0 = blockIdx.x * 128;
    const int n0 = blockIdx.y * 128;
    const int K = 2 * K0;
    const int lane = tid & 63;
    const int w = tid >> 6;
    const int wr = w >> 1, wc = w & 1;
    const int fr = lane & 15, fq = lane >> 4;
    const int srow = tid >> 2;
    const int schunk = (tid & 3) * 8;

    v4f acc[4][4];
#pragma unroll
    for (int mi = 0; mi < 4; ++mi)
#pragma unroll
        for (int ni = 0; ni < 4; ++ni)
            acc[mi][ni] = (v4f){0.f, 0.f, 0.f, 0.f};

    for (int k0 = 0; k0 < K; k0 += 32) {
        const int kk = k0 + schunk;
        const int r0 = m0 + srow, r1 = m0 + srow + 64;
        uint4 av0 = make_uint4(0, 0, 0, 0), av1 = make_uint4(0, 0, 0, 0);
        const unsigned short* Asrc = (kk < K0) ? Aagg : (Aself - K0);
        if (r0 < NN) av0 = *(const uint4*)(Asrc + (size_t)r0 * K0 + kk);
        if (r1 < NN) av1 = *(const uint4*)(Asrc + (size_t)r1 * K0 + kk);
        uint4 bv0 = *(const uint4*)(Bt + (size_t)(n0 + srow) * K + kk);
        uint4 bv1 = *(const uint4*)(Bt + (size_t)(n0 + srow + 64) * K + kk);

        __syncthreads();
        *(uint4*)(As + srow * 32 + schunk) = av0;
        *(uint4*)(As + (srow + 64) * 32 + schunk) = av1;
        *(uint4*)(Bs + srow * 32 + schunk) = bv0;
        *(uint4*)(Bs + (srow + 64) * 32 + schunk) = bv1;
        __syncthreads();

        v8bf a[4], b[4];
#pragma unroll
        for (int mi = 0; mi < 4; ++mi)
            a[mi] = *(const v8bf*)(As + (wr * 64 + mi * 16 + fr) * 32 + fq * 8);
#pragma unroll
        for (int ni = 0; ni < 4; ++ni)
            b[ni] = *(const v8bf*)(Bs + (wc * 64 + ni * 16 + fr) * 32 + fq * 8);
#pragma unroll
        for (int mi = 0; mi < 4; ++mi)
#pragma unroll
            for (int ni = 0; ni < 4; ++ni)
                acc[mi][ni] = __builtin_amdgcn_mfma_f32_16x16x32_bf16(a[mi], b[ni], acc[mi][ni], 0, 0, 0);
    }

#pragma unroll
    for (int mi = 0; mi < 4; ++mi) {
#pragma unroll
        for (int ni = 0; ni < 4; ++ni) {
            const int col = n0 + wc * 64 + ni * 16 + fr;
            const float bb = bias[col];
#pragma unroll
            for (int r = 0; r < 4; ++r) {
                const int row = m0 + wr * 64 + mi * 16 + fq * 4 + r;
                if (row < NN) {
                    float v = acc[mi][ni][r] + bb;
                    if (RELU) v = fmaxf(v, 0.f);
                    if (OUT_F32) ((float*)outp)[(size_t)row * 256 + col] = v;
                    else ((unsigned short*)outp)[(size_t)row * 256 + col] = f2b(v);
                }
            }
        }
    }
}

extern "C" void kernel_launch(void* const* d_in, const int* in_sizes, int n_in,
                              void* d_out, int out_size, void* d_ws, size_t ws_size,
                              hipStream_t stream) {
    const float* x   = (const float*)d_in[0];
    const int*   ei  = (const int*)d_in[1];
    const float* ew  = (const float*)d_in[2];
    const float* Wl0 = (const float*)d_in[3];
    const float* Wr0 = (const float*)d_in[4];
    const float* b0  = (const float*)d_in[5];
    const float* Wl1 = (const float*)d_in[6];
    const float* Wr1 = (const float*)d_in[7];
    const float* b1  = (const float*)d_in[8];
    float* out = (float*)d_out;

    const int* src = ei;
    const int* dst = ei + NE;

    // ws layout (bytes), total ~58.6 MB (same as round 5):
    //   0        dinv  f32[50000]        (204800)
    //   204800   cnt   int[50000]; cursor aliases cnt; bsum@cnt+50048
    //   409600   rp    int[50001]        (204800)
    //   614400   epk   int2[800000]      (6400000)  [pre int[] aliases head, dead before bucket]
    //   7014400  Bt0   bf16[256*256]     (131072)
    //   7145472  Bt1   bf16[256*512]     (262144)
    //   7407616  h1b   bf16[50000*256]   (25600000)
    //   33007616 aggb  bf16[50000*256]   (25600000)
    //            layer0 uses aggb[0:NN*128] as agg; aggb[NN*128:NN*256] holds xb
    char* ws = (char*)d_ws;
    float*          dinv = (float*)(ws + 0);
    int*            cnt  = (int*)(ws + 204800);
    int*            bsum = cnt + 50048;
    int*            rp   = (int*)(ws + 409600);
    int*            pre  = (int*)(ws + 614400);
    int2*           epk  = (int2*)(ws + 614400);
    unsigned short* Bt0  = (unsigned short*)(ws + 7014400);
    unsigned short* Bt1  = (unsigned short*)(ws + 7145472);
    unsigned short* h1b  = (unsigned short*)(ws + 7407616);
    unsigned short* aggb = (unsigned short*)(ws + 33007616);
    unsigned short* xb   = aggb + (size_t)NN * 128;  // dead once gather1 runs

    k_prep<<<PB_CNT + PB_BT0 + PB_BT1 + PB_XB, 256, 0, stream>>>(
        x, Wl0, Wr0, Wl1, Wr1, cnt, Bt0, Bt1, xb);
    k_hist<<<(NE + 255) / 256, 256, 0, stream>>>(dst, cnt);
    k_scan1<<<NB, SB, 0, stream>>>(cnt, pre, bsum, dinv);
    k_scan3f<<<NB, SB, 0, stream>>>(pre, bsum, rp, /*cursor=*/cnt);
    k_bucket<<<(NE + 255) / 256, 256, 0, stream>>>(src, dst, ew, cnt, epk);

    dim3 g((NN + 127) / 128, 2);
    // layer 0
    k_gather0<<<(NN * 64 + 255) / 256, 256, 0, stream>>>(xb, rp, epk, dinv, aggb);
    k_mfma<128, false, true><<<g, 256, 0, stream>>>(aggb, xb, Bt0, b0, h1b);
    // layer 1
    k_gather1<<<(NN * 64 + 255) / 256, 256, 0, stream>>>(h1b, rp, epk, dinv, aggb);
    k_mfma<256, true, false><<<g, 256, 0, stream>>>(aggb, h1b, Bt1, b1, out);
}

// Round 7
// 343.874 us; speedup vs baseline: 13.3242x; 1.0170x over previous
//
#include <hip/hip_runtime.h>

// GraphSAGE 2-layer. N=50000, E=800000, 128 -> 256 -> 256.
// Round 7: gather kernels load edge metadata once per 64-edge batch (shfl
// broadcast, 1 VMEM/edge instead of 3), nontemporal stores for agg (don't
// evict h/x rows from L2), nontemporal loads for single-pass streams.

#define NN 50000
#define NE 800000
#define SB 1024
#define NB 49  // ceil(50000/1024)

typedef __bf16 v8bf __attribute__((ext_vector_type(8)));
typedef float v4f __attribute__((ext_vector_type(4)));
typedef float nf4 __attribute__((ext_vector_type(4)));
typedef unsigned nu2 __attribute__((ext_vector_type(2)));

__device__ __forceinline__ unsigned short f2b(float f) {
    unsigned u = __float_as_uint(f);
    return (unsigned short)((u + 0x7FFFu + ((u >> 16) & 1u)) >> 16);
}
__device__ __forceinline__ float b2f(unsigned short h) {
    return __uint_as_float(((unsigned)h) << 16);
}
__device__ __forceinline__ unsigned pack2(float a, float b) {
    return (unsigned)f2b(a) | ((unsigned)f2b(b) << 16);
}

// Fused prep: zero cnt | Bt0 | Bt1 | x->bf16. Sections by blockIdx.
#define PB_CNT 196    // 50176 threads
#define PB_BT0 256    // 65536
#define PB_BT1 512    // 131072
#define PB_XB  6250   // 1.6M float4
__global__ __launch_bounds__(256) void k_prep(const float* __restrict__ x,
                                              const float* __restrict__ Wl0,
                                              const float* __restrict__ Wr0,
                                              const float* __restrict__ Wl1,
                                              const float* __restrict__ Wr1,
                                              int* __restrict__ cnt,
                                              unsigned short* __restrict__ Bt0,
                                              unsigned short* __restrict__ Bt1,
                                              unsigned short* __restrict__ xb) {
    int b = blockIdx.x;
    int tid = threadIdx.x;
    if (b < PB_CNT) {
        int i = b * 256 + tid;
        if (i < NN) cnt[i] = 0;
    } else if (b < PB_CNT + PB_BT0) {
        int idx = (b - PB_CNT) * 256 + tid;             // [0, 65536)
        int n = idx >> 8, k = idx & 255;
        float v = (k < 128) ? Wl0[(size_t)k * 256 + n] : Wr0[(size_t)(k - 128) * 256 + n];
        Bt0[idx] = f2b(v);
    } else if (b < PB_CNT + PB_BT0 + PB_BT1) {
        int idx = (b - PB_CNT - PB_BT0) * 256 + tid;    // [0, 131072)
        int n = idx >> 9, k = idx & 511;
        float v = (k < 256) ? Wl1[(size_t)k * 256 + n] : Wr1[(size_t)(k - 256) * 256 + n];
        Bt1[idx] = f2b(v);
    } else {
        int i4 = (b - PB_CNT - PB_BT0 - PB_BT1) * 256 + tid;  // [0, 1.6M)
        nf4 v = __builtin_nontemporal_load((const nf4*)x + i4);
        nu2 o;
        o.x = pack2(v.x, v.y);
        o.y = pack2(v.z, v.w);
        *((nu2*)xb + i4) = o;
    }
}

__global__ __launch_bounds__(256) void k_hist(const int* __restrict__ dst,
                                              int* __restrict__ cnt) {
    int e = blockIdx.x * 256 + threadIdx.x;
    if (e < NE) atomicAdd(&cnt[__builtin_nontemporal_load(dst + e)], 1);
}

// Phase 1: per-block scan -> pre (block-exclusive), bsum, dinv.
__global__ __launch_bounds__(SB) void k_scan1(const int* __restrict__ cnt,
                                              int* __restrict__ pre,
                                              int* __restrict__ bsum,
                                              float* __restrict__ dinv) {
    __shared__ int tmp[SB];
    const int tid = threadIdx.x;
    const int gid = blockIdx.x * SB + tid;
    int v = (gid < NN) ? cnt[gid] : 0;
    tmp[tid] = v;
    __syncthreads();
    for (int off = 1; off < SB; off <<= 1) {
        int t = (tid >= off) ? tmp[tid - off] : 0;
        __syncthreads();
        tmp[tid] += t;
        __syncthreads();
    }
    if (gid < NN) {
        pre[gid] = tmp[tid] - v;
        dinv[gid] = 1.0f / fmaxf((float)v, 1.0f);
    }
    if (tid == SB - 1) bsum[blockIdx.x] = tmp[tid];
}

// Phase 2+3 fused: wave 0 scans the NB block sums; all threads add offset.
__global__ __launch_bounds__(SB) void k_scan3f(const int* __restrict__ pre,
                                               const int* __restrict__ bsum,
                                               int* __restrict__ rp,
                                               int* __restrict__ cursor) {
    __shared__ int s_off;
    const int tid = threadIdx.x;
    if (tid < 64) {
        int orig = (tid < NB) ? bsum[tid] : 0;
        int v = orig;
        for (int off = 1; off < 64; off <<= 1) {
            int t = __shfl_up(v, off);
            if (tid >= off) v += t;
        }
        if (tid == (int)blockIdx.x) s_off = v - orig;
    }
    __syncthreads();
    const int gid = blockIdx.x * SB + tid;
    if (gid < NN) {
        int r = pre[gid] + s_off;
        rp[gid] = r;
        cursor[gid] = r;
    }
    if (gid == 0) rp[NN] = NE;
}

__global__ __launch_bounds__(256) void k_bucket(const int* __restrict__ src,
                                                const int* __restrict__ dst,
                                                const float* __restrict__ ew,
                                                int* __restrict__ cursor,
                                                int2* __restrict__ epk) {
    int e = blockIdx.x * 256 + threadIdx.x;
    if (e >= NE) return;
    int d = __builtin_nontemporal_load(dst + e);
    int s = __builtin_nontemporal_load(src + e);
    float w = __builtin_nontemporal_load(ew + e);
    int pos = atomicAdd(&cursor[d], 1);
    epk[pos] = make_int2(s, __float_as_int(w));
}

// gather0: xb bf16 [NN][128] -> aggb bf16 [NN][128] (scaled by dinv).
// 1 wave/node; edge metadata batch-loaded (lane L holds epk[b+L]) + shfl.
__global__ __launch_bounds__(256) void k_gather0(const unsigned short* __restrict__ xb,
                                                 const int* __restrict__ rp,
                                                 const int2* __restrict__ epk,
                                                 const float* __restrict__ dinv,
                                                 unsigned short* __restrict__ aggb) {
    int wid = (blockIdx.x * 256 + threadIdx.x) >> 6;
    int lane = threadIdx.x & 63;
    if (wid >= NN) return;
    int beg = rp[wid], end = rp[wid + 1];
    float di = dinv[wid];
    float ax = 0.f, ay = 0.f;
    for (int b = beg; b < end; b += 64) {
        int n = min(end - b, 64);
        int2 pk = epk[b + min(lane, n - 1)];
        int j = 0;
        for (; j + 3 < n; j += 4) {
            int s0 = __shfl(pk.x, j + 0), s1 = __shfl(pk.x, j + 1);
            int s2 = __shfl(pk.x, j + 2), s3 = __shfl(pk.x, j + 3);
            unsigned u0 = *(const unsigned*)(xb + (size_t)s0 * 128 + lane * 2);
            unsigned u1 = *(const unsigned*)(xb + (size_t)s1 * 128 + lane * 2);
            unsigned u2 = *(const unsigned*)(xb + (size_t)s2 * 128 + lane * 2);
            unsigned u3 = *(const unsigned*)(xb + (size_t)s3 * 128 + lane * 2);
            float w0 = __int_as_float(__shfl(pk.y, j + 0));
            float w1 = __int_as_float(__shfl(pk.y, j + 1));
            float w2 = __int_as_float(__shfl(pk.y, j + 2));
            float w3 = __int_as_float(__shfl(pk.y, j + 3));
            ax += w0 * b2f((unsigned short)(u0 & 0xFFFF)) + w1 * b2f((unsigned short)(u1 & 0xFFFF))
                + w2 * b2f((unsigned short)(u2 & 0xFFFF)) + w3 * b2f((unsigned short)(u3 & 0xFFFF));
            ay += w0 * b2f((unsigned short)(u0 >> 16)) + w1 * b2f((unsigned short)(u1 >> 16))
                + w2 * b2f((unsigned short)(u2 >> 16)) + w3 * b2f((unsigned short)(u3 >> 16));
        }
        for (; j < n; ++j) {
            int s = __shfl(pk.x, j);
            float w = __int_as_float(__shfl(pk.y, j));
            unsigned u = *(const unsigned*)(xb + (size_t)s * 128 + lane * 2);
            ax += w * b2f((unsigned short)(u & 0xFFFF));
            ay += w * b2f((unsigned short)(u >> 16));
        }
    }
    __builtin_nontemporal_store(pack2(ax * di, ay * di),
                                (unsigned*)(aggb + (size_t)wid * 128 + lane * 2));
}

// gather1: h1 bf16 [NN][256] -> aggb bf16 [NN][256]. 1 wave/node, 4 ch/lane.
__global__ __launch_bounds__(256) void k_gather1(const unsigned short* __restrict__ h,
                                                 const int* __restrict__ rp,
                                                 const int2* __restrict__ epk,
                                                 const float* __restrict__ dinv,
                                                 unsigned short* __restrict__ aggb) {
    int wid = (blockIdx.x * 256 + threadIdx.x) >> 6;
    int lane = threadIdx.x & 63;
    if (wid >= NN) return;
    int beg = rp[wid], end = rp[wid + 1];
    float di = dinv[wid];
    float a0 = 0.f, a1 = 0.f, a2 = 0.f, a3 = 0.f;
    for (int b = beg; b < end; b += 64) {
        int n = min(end - b, 64);
        int2 pk = epk[b + min(lane, n - 1)];
        int j = 0;
        for (; j + 3 < n; j += 4) {
            int s0 = __shfl(pk.x, j + 0), s1 = __shfl(pk.x, j + 1);
            int s2 = __shfl(pk.x, j + 2), s3 = __shfl(pk.x, j + 3);
            uint2 u0 = *(const uint2*)(h + (size_t)s0 * 256 + lane * 4);
            uint2 u1 = *(const uint2*)(h + (size_t)s1 * 256 + lane * 4);
            uint2 u2 = *(const uint2*)(h + (size_t)s2 * 256 + lane * 4);
            uint2 u3 = *(const uint2*)(h + (size_t)s3 * 256 + lane * 4);
            float w0 = __int_as_float(__shfl(pk.y, j + 0));
            float w1 = __int_as_float(__shfl(pk.y, j + 1));
            float w2 = __int_as_float(__shfl(pk.y, j + 2));
            float w3 = __int_as_float(__shfl(pk.y, j + 3));
            a0 += w0 * b2f((unsigned short)(u0.x & 0xFFFF)) + w1 * b2f((unsigned short)(u1.x & 0xFFFF))
                + w2 * b2f((unsigned short)(u2.x & 0xFFFF)) + w3 * b2f((unsigned short)(u3.x & 0xFFFF));
            a1 += w0 * b2f((unsigned short)(u0.x >> 16)) + w1 * b2f((unsigned short)(u1.x >> 16))
                + w2 * b2f((unsigned short)(u2.x >> 16)) + w3 * b2f((unsigned short)(u3.x >> 16));
            a2 += w0 * b2f((unsigned short)(u0.y & 0xFFFF)) + w1 * b2f((unsigned short)(u1.y & 0xFFFF))
                + w2 * b2f((unsigned short)(u2.y & 0xFFFF)) + w3 * b2f((unsigned short)(u3.y & 0xFFFF));
            a3 += w0 * b2f((unsigned short)(u0.y >> 16)) + w1 * b2f((unsigned short)(u1.y >> 16))
                + w2 * b2f((unsigned short)(u2.y >> 16)) + w3 * b2f((unsigned short)(u3.y >> 16));
        }
        for (; j < n; ++j) {
            int s = __shfl(pk.x, j);
            float w = __int_as_float(__shfl(pk.y, j));
            uint2 u = *(const uint2*)(h + (size_t)s * 256 + lane * 4);
            a0 += w * b2f((unsigned short)(u.x & 0xFFFF));
            a1 += w * b2f((unsigned short)(u.x >> 16));
            a2 += w * b2f((unsigned short)(u.y & 0xFFFF));
            a3 += w * b2f((unsigned short)(u.y >> 16));
        }
    }
    nu2 o;
    o.x = pack2(a0 * di, a1 * di);
    o.y = pack2(a2 * di, a3 * di);
    __builtin_nontemporal_store(o, (nu2*)(aggb + (size_t)wid * 256 + lane * 4));
}

// MFMA GEMM: C[row, 0:256] = concat(Aagg[row,:], Aself[row,:]) @ Bt^T + bias.
// 128x128 tile per block, 4 waves (2x2), 4x4 MFMA 16x16x32 per wave. bf16 in.
template <int K0, bool OUT_F32, bool RELU>
__global__ __launch_bounds__(256) void k_mfma(const unsigned short* __restrict__ Aagg,
                                              const unsigned short* __restrict__ Aself,
                                              const unsigned short* __restrict__ Bt,
                                              const float* __restrict__ bias,
                                              void* __restrict__ outp) {
    __shared__ unsigned short As[128 * 32];
    __shared__ unsigned short Bs[128 * 32];
    const int tid = threadIdx.x;
    const int m0 = blockIdx.x * 128;
    const int n0 = blockIdx.y * 128;
    const int K = 2 * K0;
    const int lane = tid & 63;
    const int w = tid >> 6;
    const int wr = w >> 1, wc = w & 1;
    const int fr = lane & 15, fq = lane >> 4;
    const int srow = tid >> 2;
    const int schunk = (tid & 3) * 8;

    v4f acc[4][4];
#pragma unroll
    for (int mi = 0; mi < 4; ++mi)
#pragma unroll
        for (int ni = 0; ni < 4; ++ni)
            acc[mi][ni] = (v4f){0.f, 0.f, 0.f, 0.f};

    for (int k0 = 0; k0 < K; k0 += 32) {
        const int kk = k0 + schunk;
        const int r0 = m0 + srow, r1 = m0 + srow + 64;
        uint4 av0 = make_uint4(0, 0, 0, 0), av1 = make_uint4(0, 0, 0, 0);
        const unsigned short* Asrc = (kk < K0) ? Aagg : (Aself - K0);
        if (r0 < NN) av0 = *(const uint4*)(Asrc + (size_t)r0 * K0 + kk);
        if (r1 < NN) av1 = *(const uint4*)(Asrc + (size_t)r1 * K0 + kk);
        uint4 bv0 = *(const uint4*)(Bt + (size_t)(n0 + srow) * K + kk);
        uint4 bv1 = *(const uint4*)(Bt + (size_t)(n0 + srow + 64) * K + kk);

        __syncthreads();
        *(uint4*)(As + srow * 32 + schunk) = av0;
        *(uint4*)(As + (srow + 64) * 32 + schunk) = av1;
        *(uint4*)(Bs + srow * 32 + schunk) = bv0;
        *(uint4*)(Bs + (srow + 64) * 32 + schunk) = bv1;
        __syncthreads();

        v8bf a[4], b[4];
#pragma unroll
        for (int mi = 0; mi < 4; ++mi)
            a[mi] = *(const v8bf*)(As + (wr * 64 + mi * 16 + fr) * 32 + fq * 8);
#pragma unroll
        for (int ni = 0; ni < 4; ++ni)
            b[ni] = *(const v8bf*)(Bs + (wc * 64 + ni * 16 + fr) * 32 + fq * 8);
#pragma unroll
        for (int mi = 0; mi < 4; ++mi)
#pragma unroll
            for (int ni = 0; ni < 4; ++ni)
                acc[mi][ni] = __builtin_amdgcn_mfma_f32_16x16x32_bf16(a[mi], b[ni], acc[mi][ni], 0, 0, 0);
    }

#pragma unroll
    for (int mi = 0; mi < 4; ++mi) {
#pragma unroll
        for (int ni = 0; ni < 4; ++ni) {
            const int col = n0 + wc * 64 + ni * 16 + fr;
            const float bb = bias[col];
#pragma unroll
            for (int r = 0; r < 4; ++r) {
                const int row = m0 + wr * 64 + mi * 16 + fq * 4 + r;
                if (row < NN) {
                    float v = acc[mi][ni][r] + bb;
                    if (RELU) v = fmaxf(v, 0.f);
                    if (OUT_F32)
                        __builtin_nontemporal_store(v, &((float*)outp)[(size_t)row * 256 + col]);
                    else
                        ((unsigned short*)outp)[(size_t)row * 256 + col] = f2b(v);
                }
            }
        }
    }
}

extern "C" void kernel_launch(void* const* d_in, const int* in_sizes, int n_in,
                              void* d_out, int out_size, void* d_ws, size_t ws_size,
                              hipStream_t stream) {
    const float* x   = (const float*)d_in[0];
    const int*   ei  = (const int*)d_in[1];
    const float* ew  = (const float*)d_in[2];
    const float* Wl0 = (const float*)d_in[3];
    const float* Wr0 = (const float*)d_in[4];
    const float* b0  = (const float*)d_in[5];
    const float* Wl1 = (const float*)d_in[6];
    const float* Wr1 = (const float*)d_in[7];
    const float* b1  = (const float*)d_in[8];
    float* out = (float*)d_out;

    const int* src = ei;
    const int* dst = ei + NE;

    // ws layout (bytes), total ~58.6 MB (same as round 6):
    //   0        dinv  f32[50000]
    //   204800   cnt   int[50000]; cursor aliases cnt; bsum@cnt+50048
    //   409600   rp    int[50001]
    //   614400   epk   int2[800000]   [pre aliases head, dead before bucket]
    //   7014400  Bt0   bf16[256*256]
    //   7145472  Bt1   bf16[256*512]
    //   7407616  h1b   bf16[50000*256]
    //   33007616 aggb  bf16[50000*256]; layer0: aggb=[NN][128], xb in 2nd half
    char* ws = (char*)d_ws;
    float*          dinv = (float*)(ws + 0);
    int*            cnt  = (int*)(ws + 204800);
    int*            bsum = cnt + 50048;
    int*            rp   = (int*)(ws + 409600);
    int*            pre  = (int*)(ws + 614400);
    int2*           epk  = (int2*)(ws + 614400);
    unsigned short* Bt0  = (unsigned short*)(ws + 7014400);
    unsigned short* Bt1  = (unsigned short*)(ws + 7145472);
    unsigned short* h1b  = (unsigned short*)(ws + 7407616);
    unsigned short* aggb = (unsigned short*)(ws + 33007616);
    unsigned short* xb   = aggb + (size_t)NN * 128;  // dead once gather1 runs

    k_prep<<<PB_CNT + PB_BT0 + PB_BT1 + PB_XB, 256, 0, stream>>>(
        x, Wl0, Wr0, Wl1, Wr1, cnt, Bt0, Bt1, xb);
    k_hist<<<(NE + 255) / 256, 256, 0, stream>>>(dst, cnt);
    k_scan1<<<NB, SB, 0, stream>>>(cnt, pre, bsum, dinv);
    k_scan3f<<<NB, SB, 0, stream>>>(pre, bsum, rp, /*cursor=*/cnt);
    k_bucket<<<(NE + 255) / 256, 256, 0, stream>>>(src, dst, ew, cnt, epk);

    dim3 g((NN + 127) / 128, 2);
    // layer 0
    k_gather0<<<(NN * 64 + 255) / 256, 256, 0, stream>>>(xb, rp, epk, dinv, aggb);
    k_mfma<128, false, true><<<g, 256, 0, stream>>>(aggb, xb, Bt0, b0, h1b);
    // layer 1
    k_gather1<<<(NN * 64 + 255) / 256, 256, 0, stream>>>(h1b, rp, epk, dinv, aggb);
    k_mfma<256, true, false><<<g, 256, 0, stream>>>(aggb, h1b, Bt1, b1, out);
}